// Round 1
// baseline (341.983 us; speedup 1.0000x reference)
//
#include <hip/hip_runtime.h>
#include <hip/hip_bf16.h>

// Problem constants
#define CIN   128
#define COUT  128
#define DD    36
#define HW    5184
#define DHW   186624          // 36*5184 ; attn per-channel plane is L*81 = same
#define PATCH 9
#define NPW   576             // patches per d-slab (HW/9)
#define L_TOT 2304            // 4 * 576
#define PP    81
#define LDSK  136             // padded k stride (128 + 8) in bf16 elems

typedef __attribute__((ext_vector_type(8))) short bf16x8;
typedef __attribute__((ext_vector_type(4))) float f32x4;

__device__ __forceinline__ short f2bf(float f) {
    unsigned u = __builtin_bit_cast(unsigned, f);
    unsigned r = (u + 0x7fffu + ((u >> 16) & 1u)) >> 16;
    return (short)r;
}

// ---------------------------------------------------------------------------
// Kernel 1: per-(c,l) nonzero count -> inv table in workspace (1.18 MB).
// v2: thread g owns pairs [4g,4g+4) == floats [324g, 324g+324) == float4s
// [81g, 81g+81).  Fully coalesced dwordx4 stream (1296 B/lane contiguous),
// compile-time segment boundaries.  Roofline ~16 us (was ~10x off).
// ---------------------------------------------------------------------------
__global__ __launch_bounds__(256) void count_nz_v2(
    const float* __restrict__ attn, float* __restrict__ inv)
{
    const int g = blockIdx.x * 256 + threadIdx.x;        // 0 .. 73727
    const float4* ap = (const float4*)attn + (size_t)g * 81;

    int cnt0 = 0, cnt1 = 0, cnt2 = 0, cnt3 = 0;

    // pair 0: floats [0,81) = f4 0..19 + f4[20].x
    #pragma unroll
    for (int f = 0; f < 20; ++f) {
        const float4 v = ap[f];
        cnt0 += (v.x != 0.f) + (v.y != 0.f) + (v.z != 0.f) + (v.w != 0.f);
    }
    {
        const float4 v = ap[20];
        cnt0 += (v.x != 0.f);
        cnt1 += (v.y != 0.f) + (v.z != 0.f) + (v.w != 0.f);
    }
    // pair 1: floats [81,162) = f4[20].yzw + f4 21..39 + f4[40].xy
    #pragma unroll
    for (int f = 21; f < 40; ++f) {
        const float4 v = ap[f];
        cnt1 += (v.x != 0.f) + (v.y != 0.f) + (v.z != 0.f) + (v.w != 0.f);
    }
    {
        const float4 v = ap[40];
        cnt1 += (v.x != 0.f) + (v.y != 0.f);
        cnt2 += (v.z != 0.f) + (v.w != 0.f);
    }
    // pair 2: floats [162,243) = f4[40].zw + f4 41..59 + f4[60].xyz
    #pragma unroll
    for (int f = 41; f < 60; ++f) {
        const float4 v = ap[f];
        cnt2 += (v.x != 0.f) + (v.y != 0.f) + (v.z != 0.f) + (v.w != 0.f);
    }
    {
        const float4 v = ap[60];
        cnt2 += (v.x != 0.f) + (v.y != 0.f) + (v.z != 0.f);
        cnt3 += (v.w != 0.f);
    }
    // pair 3: floats [243,324) = f4[60].w + f4 61..80
    #pragma unroll
    for (int f = 61; f < 81; ++f) {
        const float4 v = ap[f];
        cnt3 += (v.x != 0.f) + (v.y != 0.f) + (v.z != 0.f) + (v.w != 0.f);
    }

    float4 o;
    o.x = 1.0f / ((float)cnt0 + 1e-5f);
    o.y = 1.0f / ((float)cnt1 + 1e-5f);
    o.z = 1.0f / ((float)cnt2 + 1e-5f);
    o.w = 1.0f / ((float)cnt3 + 1e-5f);
    *(float4*)(inv + (size_t)g * 4) = o;
}

// ---------------------------------------------------------------------------
// Kernel 2: fused 1x1x1-conv GEMM + attention epilogue.
// Logical work: (d fastest, hwblk) so the 9 d-blocks sharing a patch's attn
// lines are contiguous; bijective XCD-chunk swizzle (nwg=2916, q=364, r=4)
// keeps each contiguous run on one XCD's L2 -> attn fetched once from HBM.
// ---------------------------------------------------------------------------
__global__ __launch_bounds__(256) void fused_main(
    const float* __restrict__ x,     // [128][36][5184]
    const float* __restrict__ attn,  // [128][2304][81]
    const float* __restrict__ W,     // [128][128]
    const float* __restrict__ bia,   // [128]
    const float* __restrict__ inv,   // [128][2304]
    float* __restrict__ out)         // [128][36][5184]
{
    __shared__ __align__(16) short xs[64][LDSK];   // transposed bf16 x-tile [n][k]

    const int t    = threadIdx.x;
    const int wv   = t >> 6;
    const int lane = t & 63;
    const int col  = lane & 15;
    const int quad = lane >> 4;

    // ---- bijective XCD chunk swizzle: nwg=2916, q=364, r=4 (m204 formula) ----
    const int bidRaw = blockIdx.x;
    const int xcd = bidRaw & 7;
    const int loc = bidRaw >> 3;
    const int wgid = (xcd < 4 ? xcd * 365 : 1460 + (xcd - 4) * 364) + loc;

    const int d      = wgid % 36;             // fastest: d-neighbors contiguous
    const int hwblk  = wgid / 36;             // 0..80
    const int hwbase = hwblk * 64;
    const int lbase  = (d / 9) * NPW;         // l = lbase + hw/9
    const int ii     = d % 9;                 // kernel-row index within patch

    // ---- stage x[:, d, hwbase..+64) -> LDS transposed bf16 [n][k] ----
    // 2 cin rows per iteration, packed dword LDS writes (halves write count
    // and conflict cycles vs scalar u16 writes).
    #pragma unroll
    for (int e = t; e < 1024; e += 256) {
        const int rp  = e >> 4;               // row-pair 0..63
        const int f4  = e & 15;
        const int row = rp * 2;
        const float* xp = x + (size_t)row * DHW + (size_t)d * HW + hwbase + f4 * 4;
        const float4 va = *(const float4*)xp;
        const float4 vb = *(const float4*)(xp + DHW);
        const int n0 = f4 * 4;
        const unsigned p0 = (unsigned short)f2bf(va.x) | ((unsigned)(unsigned short)f2bf(vb.x) << 16);
        const unsigned p1 = (unsigned short)f2bf(va.y) | ((unsigned)(unsigned short)f2bf(vb.y) << 16);
        const unsigned p2 = (unsigned short)f2bf(va.z) | ((unsigned)(unsigned short)f2bf(vb.z) << 16);
        const unsigned p3 = (unsigned short)f2bf(va.w) | ((unsigned)(unsigned short)f2bf(vb.w) << 16);
        *(unsigned*)&xs[n0 + 0][row] = p0;
        *(unsigned*)&xs[n0 + 1][row] = p1;
        *(unsigned*)&xs[n0 + 2][row] = p2;
        *(unsigned*)&xs[n0 + 3][row] = p3;
    }

    // ---- A fragments: W rows for this wave (Cout tile = wv*32 .. +32) ----
    const int wbase = wv * 32;
    bf16x8 afrag[2][4];
    #pragma unroll
    for (int mt = 0; mt < 2; ++mt) {
        const int m = wbase + mt * 16 + col;
        #pragma unroll
        for (int s = 0; s < 4; ++s) {
            const float4* wp4 = (const float4*)(W + m * 128 + s * 32 + quad * 8);
            float4 w0 = wp4[0], w1 = wp4[1];
            bf16x8 f;
            f[0] = f2bf(w0.x); f[1] = f2bf(w0.y); f[2] = f2bf(w0.z); f[3] = f2bf(w0.w);
            f[4] = f2bf(w1.x); f[5] = f2bf(w1.y); f[6] = f2bf(w1.z); f[7] = f2bf(w1.w);
            afrag[mt][s] = f;
        }
    }
    float bias[2][4];
    #pragma unroll
    for (int mt = 0; mt < 2; ++mt)
        #pragma unroll
        for (int r = 0; r < 4; ++r)
            bias[mt][r] = bia[wbase + mt * 16 + quad * 4 + r];

    __syncthreads();

    // ---- GEMM: 128(Cout) x 64(n) x 128(K), 16x16x32 MFMA ----
    f32x4 acc[2][4];
    #pragma unroll
    for (int mt = 0; mt < 2; ++mt)
        #pragma unroll
        for (int tt = 0; tt < 4; ++tt)
            acc[mt][tt] = (f32x4){0.f, 0.f, 0.f, 0.f};

    #pragma unroll
    for (int s = 0; s < 4; ++s) {
        bf16x8 bfrag[4];
        #pragma unroll
        for (int tt = 0; tt < 4; ++tt)
            bfrag[tt] = *(const bf16x8*)&xs[tt * 16 + col][s * 32 + quad * 8];
        #pragma unroll
        for (int mt = 0; mt < 2; ++mt)
            #pragma unroll
            for (int tt = 0; tt < 4; ++tt)
                acc[mt][tt] = __builtin_amdgcn_mfma_f32_16x16x32_bf16(
                    afrag[mt][s], bfrag[tt], acc[mt][tt], 0, 0, 0);
    }

    // ---- epilogue: y=acc+bias ; out = lrelu(y*(y + a*inv + 1)) ----
    #pragma unroll
    for (int tt = 0; tt < 4; ++tt) {
        const int n  = tt * 16 + col;
        const int hw = hwbase + n;
        const int p  = hw / 9;
        const int jj = hw - p * 9;
        const int l  = lbase + p;
        const int kk = ii * 9 + jj;
        #pragma unroll
        for (int mt = 0; mt < 2; ++mt) {
            #pragma unroll
            for (int r = 0; r < 4; ++r) {
                const int c = wbase + mt * 16 + quad * 4 + r;
                const float y  = acc[mt][tt][r] + bias[mt][r];
                const float a  = attn[(size_t)c * DHW + (size_t)l * PP + kk];
                const float iv = inv[c * L_TOT + l];
                const float v  = y * (y + a * iv + 1.0f);
                // non-temporal: keep 96 MB of write traffic from evicting
                // the attn lines shared with the d-neighbor blocks in L2
                __builtin_nontemporal_store((v >= 0.f) ? v : 0.2f * v,
                    out + (size_t)c * DHW + (size_t)d * HW + hw);
            }
        }
    }
}

// ---------------------------------------------------------------------------
// Fallback (round-1 kernel, known-good) in case ws is too small for inv table.
// ---------------------------------------------------------------------------
__global__ __launch_bounds__(256) void fused_cross_head_fallback(
    const float* __restrict__ x, const float* __restrict__ attn,
    const float* __restrict__ W, const float* __restrict__ bia,
    float* __restrict__ out)
{
    __shared__ __align__(16) short xs[2][48][LDSK];
    __shared__ float inv_lds[COUT][4];

    const int t = threadIdx.x, wv = t >> 6, lane = t & 63;
    const int col = lane & 15, quad = lane >> 4;
    const int blk = blockIdx.x;
    const int pd = blk / 144, hwblk = blk - pd * 144;
    const int hwbase = hwblk * 36;
    const int lbase = pd * NPW + hwblk * 4;

    for (int pair = t; pair < 512; pair += 256) {
        const int c = pair >> 2, p = pair & 3;
        const float* ap = attn + (size_t)c * DHW + (size_t)(lbase + p) * PP;
        int cnt = 0;
        #pragma unroll 27
        for (int q = 0; q < PP; ++q) cnt += (ap[q] != 0.0f) ? 1 : 0;
        inv_lds[c][p] = 1.0f / ((float)cnt + 1e-5f);
    }
    const int wbase = wv * 32;
    bf16x8 afrag[2][4];
    #pragma unroll
    for (int mt = 0; mt < 2; ++mt) {
        const int m = wbase + mt * 16 + col;
        #pragma unroll
        for (int s = 0; s < 4; ++s) {
            const float4* wp4 = (const float4*)(W + m * 128 + s * 32 + quad * 8);
            float4 w0 = wp4[0], w1 = wp4[1];
            bf16x8 f;
            f[0] = f2bf(w0.x); f[1] = f2bf(w0.y); f[2] = f2bf(w0.z); f[3] = f2bf(w0.w);
            f[4] = f2bf(w1.x); f[5] = f2bf(w1.y); f[6] = f2bf(w1.z); f[7] = f2bf(w1.w);
            afrag[mt][s] = f;
        }
    }
    float bias[2][4];
    #pragma unroll
    for (int mt = 0; mt < 2; ++mt)
        #pragma unroll
        for (int r = 0; r < 4; ++r)
            bias[mt][r] = bia[wbase + mt * 16 + quad * 4 + r];

    for (int i = 0; i < 9; ++i) {
        const int buf = i & 1;
        const int d = pd * PATCH + i;
        for (int e = t; e < 1152; e += 256) {
            const int row = e / 9, f4 = e - row * 9;
            const float4 v = *(const float4*)(x + (size_t)row * DHW + (size_t)d * HW
                                              + hwbase + f4 * 4);
            const int n0 = f4 * 4;
            xs[buf][n0 + 0][row] = f2bf(v.x);
            xs[buf][n0 + 1][row] = f2bf(v.y);
            xs[buf][n0 + 2][row] = f2bf(v.z);
            xs[buf][n0 + 3][row] = f2bf(v.w);
        }
        __syncthreads();
        f32x4 acc[2][3];
        #pragma unroll
        for (int mt = 0; mt < 2; ++mt)
            #pragma unroll
            for (int tt = 0; tt < 3; ++tt)
                acc[mt][tt] = (f32x4){0.f, 0.f, 0.f, 0.f};
        #pragma unroll
        for (int s = 0; s < 4; ++s) {
            bf16x8 bfrag[3];
            #pragma unroll
            for (int tt = 0; tt < 3; ++tt)
                bfrag[tt] = *(const bf16x8*)&xs[buf][tt * 16 + col][s * 32 + quad * 8];
            #pragma unroll
            for (int mt = 0; mt < 2; ++mt)
                #pragma unroll
                for (int tt = 0; tt < 3; ++tt)
                    acc[mt][tt] = __builtin_amdgcn_mfma_f32_16x16x32_bf16(
                        afrag[mt][s], bfrag[tt], acc[mt][tt], 0, 0, 0);
        }
        #pragma unroll
        for (int tt = 0; tt < 3; ++tt) {
            const int n = tt * 16 + col;
            if (n < 36) {
                const int p = n / 9, jj = n - p * 9, kk = i * 9 + jj;
                #pragma unroll
                for (int mt = 0; mt < 2; ++mt) {
                    #pragma unroll
                    for (int r = 0; r < 4; ++r) {
                        const int c = wbase + mt * 16 + quad * 4 + r;
                        const float y = acc[mt][tt][r] + bias[mt][r];
                        const float a = attn[(size_t)c * DHW + (size_t)(lbase + p) * PP + kk];
                        const float v = y * (y + a * inv_lds[c][p] + 1.0f);
                        out[(size_t)c * DHW + (size_t)d * HW + hwbase + n] =
                            (v >= 0.f) ? v : 0.2f * v;
                    }
                }
            }
        }
    }
}

extern "C" void kernel_launch(void* const* d_in, const int* in_sizes, int n_in,
                              void* d_out, int out_size, void* d_ws, size_t ws_size,
                              hipStream_t stream) {
    const float* x    = (const float*)d_in[0];
    const float* attn = (const float*)d_in[1];
    const float* W    = (const float*)d_in[2];
    const float* b    = (const float*)d_in[3];
    float* out        = (float*)d_out;

    const size_t inv_bytes = (size_t)COUT * L_TOT * sizeof(float);  // 1.18 MB
    if (ws_size >= inv_bytes) {
        float* inv = (float*)d_ws;
        // 73728 threads, 4 (c,l)-pairs each = 294912 pairs
        count_nz_v2<<<dim3(288), dim3(256), 0, stream>>>(attn, inv);
        fused_main<<<dim3(36 * 81), dim3(256), 0, stream>>>(x, attn, W, b, inv, out);
    } else {
        fused_cross_head_fallback<<<dim3(576), dim3(256), 0, stream>>>(x, attn, W, b, out);
    }
}

// Round 2
// 325.385 us; speedup vs baseline: 1.0510x; 1.0510x over previous
//
#include <hip/hip_runtime.h>

// Problem constants
#define CIN   128
#define COUT  128
#define DD    36
#define HW    5184
#define DHW   186624          // 36*5184 ; attn per-channel plane is L*81 = same
#define PATCH 9
#define NPW   576             // patches per d-slab (HW/9)
#define L_TOT 2304            // 4 * 576
#define PP    81
#define LDSK  136             // padded k stride (128 + 8) in bf16 elems

typedef __attribute__((ext_vector_type(8))) short bf16x8;
typedef __attribute__((ext_vector_type(4))) float f32x4;

__device__ __forceinline__ short f2bf(float f) {
    unsigned u = __builtin_bit_cast(unsigned, f);
    unsigned r = (u + 0x7fffu + ((u >> 16) & 1u)) >> 16;
    return (short)r;
}

// ---------------------------------------------------------------------------
// Unified kernel: block = (pd 0..3, hwblk 0..143) owns a patch-aligned tile of
// 4 patches x 9 d-rows x 128 Cout.  It sees all 81 attn elements of each of
// its 512 (c,l) pairs, so the nonzero count is computed in-block (ballot +
// popcount, fully coalesced 256B reads) with ZERO extra global traffic -- the
// standalone count kernel (~100 us + a full 95.6 MB attn pass) is eliminated.
// The count pre-pass also warms this XCD's L2 with the 166 KB attn tile, so
// the epilogue's scattered attn reads hit L2/L3.  The 9 GEMM phases are
// software-pipelined: next-phase x loads issue before the MFMAs and the LDS
// write lands after the epilogue (HBM latency hides under epilogue work).
// ---------------------------------------------------------------------------
__global__ __launch_bounds__(256) void fused_all(
    const float* __restrict__ x,     // [128][36][5184]
    const float* __restrict__ attn,  // [128][2304][81]
    const float* __restrict__ W,     // [128][128]
    const float* __restrict__ bia,   // [128]
    float* __restrict__ out)         // [128][36][5184]
{
    __shared__ __align__(16) short xs[2][48][LDSK];   // double-buffered [n][k]
    __shared__ float inv_lds[COUT][4];

    const int t    = threadIdx.x;
    const int wv   = t >> 6;
    const int lane = t & 63;
    const int col  = lane & 15;
    const int quad = lane >> 4;

    // XCD-chunked swizzle (576 = 8*72): consecutive logical tiles -> same XCD
    const int bid = blockIdx.x;
    const int w   = (bid & 7) * 72 + (bid >> 3);
    const int pd     = w / 144;
    const int hwblk  = w - pd * 144;
    const int hwbase = hwblk * 36;            // patch-aligned (36 = 4*9)
    const int lbase  = pd * NPW + hwblk * 4;  // 4 patches owned by this block
    const int d0     = pd * PATCH;

    // ---- issue phase-0 x prefetch (completes during the count pre-pass) ----
    // stage elems: rp (row-pair 0..63) x f4 (0..8), 576 total, <=3 per thread
    float4 pva[3], pvb[3];
    #pragma unroll
    for (int it = 0; it < 3; ++it) {
        const int e = t + it * 256;
        if (e < 576) {
            const int rp = e / 9, f4 = e - rp * 9;
            const float* xp = x + (size_t)(rp * 2) * DHW + (size_t)d0 * HW
                            + hwbase + f4 * 4;
            pva[it] = *(const float4*)xp;
            pvb[it] = *(const float4*)(xp + DHW);
        }
    }

    // ---- ballot-based nonzero count: each wave counts 32 c-planes ----
    // Per c: 324 floats (4 patches) read as 5 full 64-lane windows + 4-float
    // tail; patch boundaries (81/162/243) fall at compile-time lane positions.
    {
        const size_t abase = (size_t)lbase * PP;
        const unsigned long long m17 = (1ull << 17) - 1;
        const unsigned long long m34 = (1ull << 34) - 1;
        const unsigned long long m51 = (1ull << 51) - 1;
        #pragma unroll 4
        for (int it = 0; it < 32; ++it) {
            const int c = wv * 32 + it;
            const float* ap = attn + (size_t)c * DHW + abase;
            const float v0 = ap[lane];
            const float v1 = ap[64 + lane];
            const float v2 = ap[128 + lane];
            const float v3 = ap[192 + lane];
            const float v4 = ap[256 + lane];
            const float v5 = (lane < 4) ? ap[320 + lane] : 0.0f;
            const unsigned long long b0 = __ballot(v0 != 0.0f);
            const unsigned long long b1 = __ballot(v1 != 0.0f);
            const unsigned long long b2 = __ballot(v2 != 0.0f);
            const unsigned long long b3 = __ballot(v3 != 0.0f);
            const unsigned long long b4 = __ballot(v4 != 0.0f);
            const unsigned long long b5 = __ballot(v5 != 0.0f);
            // patch0 = floats [0,81), patch1 = [81,162), patch2 = [162,243),
            // patch3 = [243,324)
            const int c0 = __popcll(b0) + __popcll(b1 & m17);
            const int c1 = __popcll(b1 & ~m17) + __popcll(b2 & m34);
            const int c2 = __popcll(b2 & ~m34) + __popcll(b3 & m51);
            const int c3 = __popcll(b3 & ~m51) + __popcll(b4) + __popcll(b5);
            if (lane < 4) {
                const int cc = (lane == 0) ? c0 : (lane == 1) ? c1
                             : (lane == 2) ? c2 : c3;
                inv_lds[c][lane] = 1.0f / ((float)cc + 1e-5f);
            }
        }
    }

    // ---- A fragments: W rows for this wave (Cout tile = wv*32 .. +32) ----
    const int wbase = wv * 32;
    bf16x8 afrag[2][4];
    #pragma unroll
    for (int mt = 0; mt < 2; ++mt) {
        const int m = wbase + mt * 16 + col;
        #pragma unroll
        for (int s = 0; s < 4; ++s) {
            const float4* wp4 = (const float4*)(W + m * 128 + s * 32 + quad * 8);
            float4 w0 = wp4[0], w1 = wp4[1];
            bf16x8 f;
            f[0] = f2bf(w0.x); f[1] = f2bf(w0.y); f[2] = f2bf(w0.z); f[3] = f2bf(w0.w);
            f[4] = f2bf(w1.x); f[5] = f2bf(w1.y); f[6] = f2bf(w1.z); f[7] = f2bf(w1.w);
            afrag[mt][s] = f;
        }
    }
    float bias[2][4];
    #pragma unroll
    for (int mt = 0; mt < 2; ++mt)
        #pragma unroll
        for (int r = 0; r < 4; ++r)
            bias[mt][r] = bia[wbase + mt * 16 + quad * 4 + r];

    // ---- write phase-0 stage to LDS (prefetch has long since landed) ----
    #pragma unroll
    for (int it = 0; it < 3; ++it) {
        const int e = t + it * 256;
        if (e < 576) {
            const int rp = e / 9, f4 = e - rp * 9;
            const int n0 = f4 * 4, row = rp * 2;
            const float4 va = pva[it], vb = pvb[it];
            const unsigned p0 = (unsigned short)f2bf(va.x) | ((unsigned)(unsigned short)f2bf(vb.x) << 16);
            const unsigned p1 = (unsigned short)f2bf(va.y) | ((unsigned)(unsigned short)f2bf(vb.y) << 16);
            const unsigned p2 = (unsigned short)f2bf(va.z) | ((unsigned)(unsigned short)f2bf(vb.z) << 16);
            const unsigned p3 = (unsigned short)f2bf(va.w) | ((unsigned)(unsigned short)f2bf(vb.w) << 16);
            *(unsigned*)&xs[0][n0 + 0][row] = p0;
            *(unsigned*)&xs[0][n0 + 1][row] = p1;
            *(unsigned*)&xs[0][n0 + 2][row] = p2;
            *(unsigned*)&xs[0][n0 + 3][row] = p3;
        }
    }
    __syncthreads();

    // ---- 9 pipelined phases: prefetch(ii+1) || GEMM(ii)+epilogue(ii) ----
    int buf = 0;
    for (int ii = 0; ii < 9; ++ii) {
        // issue next-phase global loads (latency hides under MFMA+epilogue)
        if (ii < 8) {
            #pragma unroll
            for (int it = 0; it < 3; ++it) {
                const int e = t + it * 256;
                if (e < 576) {
                    const int rp = e / 9, f4 = e - rp * 9;
                    const float* xp = x + (size_t)(rp * 2) * DHW
                                    + (size_t)(d0 + ii + 1) * HW + hwbase + f4 * 4;
                    pva[it] = *(const float4*)xp;
                    pvb[it] = *(const float4*)(xp + DHW);
                }
            }
        }

        // GEMM: 128(Cout) x 36(n, padded to 48) x 128(K)
        f32x4 acc[2][3];
        #pragma unroll
        for (int mt = 0; mt < 2; ++mt)
            #pragma unroll
            for (int tt = 0; tt < 3; ++tt)
                acc[mt][tt] = (f32x4){0.f, 0.f, 0.f, 0.f};

        #pragma unroll
        for (int s = 0; s < 4; ++s) {
            bf16x8 bfrag[3];
            #pragma unroll
            for (int tt = 0; tt < 3; ++tt)
                bfrag[tt] = *(const bf16x8*)&xs[buf][tt * 16 + col][s * 32 + quad * 8];
            #pragma unroll
            for (int mt = 0; mt < 2; ++mt)
                #pragma unroll
                for (int tt = 0; tt < 3; ++tt)
                    acc[mt][tt] = __builtin_amdgcn_mfma_f32_16x16x32_bf16(
                        afrag[mt][s], bfrag[tt], acc[mt][tt], 0, 0, 0);
        }

        // epilogue: attn reads hit the L2 tile warmed by the count pre-pass
        const int d = d0 + ii;
        #pragma unroll
        for (int tt = 0; tt < 3; ++tt) {
            const int n = tt * 16 + col;
            if (n < 36) {
                const int p  = n / 9;
                const int jj = n - p * 9;
                const int kk = ii * 9 + jj;
                const int l  = lbase + p;
                #pragma unroll
                for (int mt = 0; mt < 2; ++mt) {
                    #pragma unroll
                    for (int r = 0; r < 4; ++r) {
                        const int c = wbase + mt * 16 + quad * 4 + r;
                        const float y = acc[mt][tt][r] + bias[mt][r];
                        const float a = attn[(size_t)c * DHW + (size_t)l * PP + kk];
                        const float v = y * (y + a * inv_lds[c][p] + 1.0f);
                        out[(size_t)c * DHW + (size_t)d * HW + hwbase + n] =
                            (v >= 0.f) ? v : 0.2f * v;
                    }
                }
            }
        }

        // convert + LDS-write next stage (writes buf^1: no conflict with any
        // wave still reading buf); barrier publishes it for phase ii+1
        if (ii < 8) {
            #pragma unroll
            for (int it = 0; it < 3; ++it) {
                const int e = t + it * 256;
                if (e < 576) {
                    const int rp = e / 9, f4 = e - rp * 9;
                    const int n0 = f4 * 4, row = rp * 2;
                    const float4 va = pva[it], vb = pvb[it];
                    const unsigned p0 = (unsigned short)f2bf(va.x) | ((unsigned)(unsigned short)f2bf(vb.x) << 16);
                    const unsigned p1 = (unsigned short)f2bf(va.y) | ((unsigned)(unsigned short)f2bf(vb.y) << 16);
                    const unsigned p2 = (unsigned short)f2bf(va.z) | ((unsigned)(unsigned short)f2bf(vb.z) << 16);
                    const unsigned p3 = (unsigned short)f2bf(va.w) | ((unsigned)(unsigned short)f2bf(vb.w) << 16);
                    *(unsigned*)&xs[buf ^ 1][n0 + 0][row] = p0;
                    *(unsigned*)&xs[buf ^ 1][n0 + 1][row] = p1;
                    *(unsigned*)&xs[buf ^ 1][n0 + 2][row] = p2;
                    *(unsigned*)&xs[buf ^ 1][n0 + 3][row] = p3;
                }
            }
        }
        __syncthreads();
        buf ^= 1;
    }
}

extern "C" void kernel_launch(void* const* d_in, const int* in_sizes, int n_in,
                              void* d_out, int out_size, void* d_ws, size_t ws_size,
                              hipStream_t stream) {
    const float* x    = (const float*)d_in[0];
    const float* attn = (const float*)d_in[1];
    const float* W    = (const float*)d_in[2];
    const float* b    = (const float*)d_in[3];
    float* out        = (float*)d_out;

    // Single fused kernel: count + GEMM + epilogue, no workspace needed.
    fused_all<<<dim3(576), dim3(256), 0, stream>>>(x, attn, W, b, out);
}

// Round 3
// 290.237 us; speedup vs baseline: 1.1783x; 1.1211x over previous
//
#include <hip/hip_runtime.h>

// Problem constants
#define CIN   128
#define COUT  128
#define DD    36
#define HW    5184
#define DHW   186624          // 36*5184 ; attn per-channel plane is L*81 = same
#define PATCH 9
#define NPW   576             // patches per d-slab (HW/9)
#define L_TOT 2304            // 4 * 576
#define PP    81
#define LDSK  136             // padded k stride (128 + 8) in bf16 elems

typedef __attribute__((ext_vector_type(8))) short bf16x8;
typedef __attribute__((ext_vector_type(4))) float f32x4;

__device__ __forceinline__ short f2bf(float f) {
    unsigned u = __builtin_bit_cast(unsigned, f);
    unsigned r = (u + 0x7fffu + ((u >> 16) & 1u)) >> 16;
    return (short)r;
}
__device__ __forceinline__ float bf2f(short s) {
    return __builtin_bit_cast(float, ((unsigned)(unsigned short)s) << 16);
}

// ---------------------------------------------------------------------------
// Kernel 1: nonzero counts via wave ballots.  One wave handles a 4-patch
// group = 324 floats = exactly 81 ALIGNED float4s (324*4B = 81*16B): lanes
// 0..63 load f4[lane], lanes 0..16 load f4[64+lane].  8 ballots + popcounts
// with compile-time patch-boundary masks.  Pure coalesced streaming of the
// 95.6 MB attn tensor (also warms L3 for kernel 2).
// ---------------------------------------------------------------------------
__global__ __launch_bounds__(256) void count_ballot(
    const float* __restrict__ attn, float* __restrict__ inv)
{
    const int wv   = threadIdx.x >> 6;
    const int lane = threadIdx.x & 63;
    const int w    = blockIdx.x * 4 + wv;      // wave id 0..18431

    // patch-boundary masks (float index f = 4*L + comp; patch = f/81)
    const unsigned long long P0X = (1ull << 21) - 1;             // L 0..20
    const unsigned long long P0Y = (1ull << 20) - 1;             // L 0..19
    const unsigned long long P1X = ((1ull << 20) - 1) << 21;     // L 21..40
    const unsigned long long P1Y = ((1ull << 21) - 1) << 20;     // L 20..40
    const unsigned long long P1Z = ((1ull << 20) - 1) << 20;     // L 20..39
    const unsigned long long P2X = ((1ull << 20) - 1) << 41;     // L 41..60
    const unsigned long long P2Z = ((1ull << 21) - 1) << 40;     // L 40..60
    const unsigned long long P2W = ((1ull << 20) - 1) << 40;     // L 40..59
    const unsigned long long P3X = 0x7ull << 61;                 // L 61..63
    const unsigned long long P3W = 0xFull << 60;                 // L 60..63
    const unsigned long long TL  = (1ull << 17) - 1;             // tail lanes

    #pragma unroll
    for (int k = 0; k < 4; ++k) {
        const int g = w * 4 + k;               // 4-patch group 0..73727
        const float4* ap = (const float4*)attn + (size_t)g * 81;
        const float4 va = ap[lane];
        float4 vb = (float4){0.f, 0.f, 0.f, 0.f};
        if (lane < 17) vb = ap[64 + lane];

        const unsigned long long bx = __ballot(va.x != 0.f);
        const unsigned long long by = __ballot(va.y != 0.f);
        const unsigned long long bz = __ballot(va.z != 0.f);
        const unsigned long long bw = __ballot(va.w != 0.f);
        const unsigned long long tx = __ballot(vb.x != 0.f);
        const unsigned long long ty = __ballot(vb.y != 0.f);
        const unsigned long long tz = __ballot(vb.z != 0.f);
        const unsigned long long tw = __ballot(vb.w != 0.f);

        const int c0 = __popcll(bx & P0X) + __popcll(by & P0Y)
                     + __popcll(bz & P0Y) + __popcll(bw & P0Y);
        const int c1 = __popcll(bx & P1X) + __popcll(by & P1Y)
                     + __popcll(bz & P1Z) + __popcll(bw & P1Z);
        const int c2 = __popcll(bx & P2X) + __popcll(by & P2X)
                     + __popcll(bz & P2Z) + __popcll(bw & P2W);
        const int c3 = __popcll(bx & P3X) + __popcll(by & P3X)
                     + __popcll(bz & P3X) + __popcll(bw & P3W)
                     + __popcll(tx & TL) + __popcll(ty & TL)
                     + __popcll(tz & TL) + __popcll(tw & TL);

        if (lane < 4) {
            const int cc = (lane == 0) ? c0 : (lane == 1) ? c1
                         : (lane == 2) ? c2 : c3;
            inv[(size_t)g * 4 + lane] = 1.0f / ((float)cc + 1e-5f);
        }
    }
}

// ---------------------------------------------------------------------------
// Kernel 2: fused 1x1x1-conv GEMM + attention epilogue.
// v3: the epilogue's per-thread scattered global attn/inv reads (the latency
// bottleneck: 32 loads to lines ~746KB apart, batched by VGPR budget) are
// replaced by a cooperative bulk LDS stage before the barrier: the block
// needs exactly attn[c][lbase+p0+q][ii*9+j] for 128c x 8q x 9j (36B chunks)
// -> 19.5KB bf16 tile + 4KB inv tile.  LDS total 40KB -> 4 blocks/CU; bulk
// loads across ~16 waves/CU hide HBM/L3 latency.  64-wide tiles keep out
// writes 256B-aligned (full lines); plain stores (NT hurt: partial flushes).
// ---------------------------------------------------------------------------
__global__ __launch_bounds__(256, 4) void fused_main_v3(
    const float* __restrict__ x,     // [128][36][5184]
    const float* __restrict__ attn,  // [128][2304][81]
    const float* __restrict__ W,     // [128][128]
    const float* __restrict__ bia,   // [128]
    const float* __restrict__ inv,   // [128][2304]
    float* __restrict__ out)         // [128][36][5184]
{
    __shared__ __align__(16) short xs[64][LDSK];   // 17408 B, x-tile [n][k]
    __shared__ short attn_s[128][76];              // 19456 B (72 used + pad)
    __shared__ float inv_s[128][8];                //  4096 B

    const int t    = threadIdx.x;
    const int wv   = t >> 6;
    const int lane = t & 63;
    const int col  = lane & 15;
    const int quad = lane >> 4;

    // bijective XCD chunk swizzle: nwg=2916, q=364, r=4 (m204 formula)
    const int bidRaw = blockIdx.x;
    const int xcd = bidRaw & 7;
    const int loc = bidRaw >> 3;
    const int wgid = (xcd < 4 ? xcd * 365 : 1460 + (xcd - 4) * 364) + loc;

    const int d      = wgid % 36;             // fastest: d-neighbors share attn lines
    const int hwblk  = wgid / 36;             // 0..80
    const int hwbase = hwblk * 64;
    const int lbase  = (d / 9) * NPW;
    const int ii     = d % 9;                 // kernel-row index within patch
    const int p0     = hwbase / 9;            // first patch touched (8 total)

    // ---- stage x[:, d, hwbase..+64) -> LDS transposed bf16 [n][k] ----
    #pragma unroll
    for (int e = t; e < 1024; e += 256) {
        const int rp  = e >> 4;               // row-pair 0..63
        const int f4  = e & 15;
        const int row = rp * 2;
        const float* xp = x + (size_t)row * DHW + (size_t)d * HW + hwbase + f4 * 4;
        const float4 va = *(const float4*)xp;
        const float4 vb = *(const float4*)(xp + DHW);
        const int n0 = f4 * 4;
        const unsigned p0w = (unsigned short)f2bf(va.x) | ((unsigned)(unsigned short)f2bf(vb.x) << 16);
        const unsigned p1w = (unsigned short)f2bf(va.y) | ((unsigned)(unsigned short)f2bf(vb.y) << 16);
        const unsigned p2w = (unsigned short)f2bf(va.z) | ((unsigned)(unsigned short)f2bf(vb.z) << 16);
        const unsigned p3w = (unsigned short)f2bf(va.w) | ((unsigned)(unsigned short)f2bf(vb.w) << 16);
        *(unsigned*)&xs[n0 + 0][row] = p0w;
        *(unsigned*)&xs[n0 + 1][row] = p1w;
        *(unsigned*)&xs[n0 + 2][row] = p2w;
        *(unsigned*)&xs[n0 + 3][row] = p3w;
    }

    // ---- stage attn tile: 128c x 8q x 9j scalars (adjacent threads read
    // adjacent j -> 36B-chunk locality), bf16 into LDS ----
    #pragma unroll
    for (int k = 0; k < 36; ++k) {
        const int e   = t + 256 * k;          // 0..9215
        const int c   = e / 72;
        const int rem = e - c * 72;           // q*9 + j
        const int q   = rem / 9;
        const int j   = rem - q * 9;
        const float a = attn[(size_t)c * DHW + (size_t)(lbase + p0 + q) * PP
                             + ii * 9 + j];
        attn_s[c][rem] = f2bf(a);
    }
    // ---- stage inv tile: 128c x 8q ----
    #pragma unroll
    for (int k = 0; k < 4; ++k) {
        const int e = t + 256 * k;            // 0..1023
        const int c = e >> 3, q = e & 7;
        inv_s[c][q] = inv[(size_t)c * L_TOT + lbase + p0 + q];
    }

    // ---- A fragments: W rows for this wave (Cout tile = wv*32 .. +32) ----
    const int wbase = wv * 32;
    bf16x8 afrag[2][4];
    #pragma unroll
    for (int mt = 0; mt < 2; ++mt) {
        const int m = wbase + mt * 16 + col;
        #pragma unroll
        for (int s = 0; s < 4; ++s) {
            const float4* wp4 = (const float4*)(W + m * 128 + s * 32 + quad * 8);
            float4 w0 = wp4[0], w1 = wp4[1];
            bf16x8 f;
            f[0] = f2bf(w0.x); f[1] = f2bf(w0.y); f[2] = f2bf(w0.z); f[3] = f2bf(w0.w);
            f[4] = f2bf(w1.x); f[5] = f2bf(w1.y); f[6] = f2bf(w1.z); f[7] = f2bf(w1.w);
            afrag[mt][s] = f;
        }
    }
    float bias[2][4];
    #pragma unroll
    for (int mt = 0; mt < 2; ++mt)
        #pragma unroll
        for (int r = 0; r < 4; ++r)
            bias[mt][r] = bia[wbase + mt * 16 + quad * 4 + r];

    __syncthreads();

    // ---- GEMM: 128(Cout) x 64(n) x 128(K), 16x16x32 MFMA ----
    f32x4 acc[2][4];
    #pragma unroll
    for (int mt = 0; mt < 2; ++mt)
        #pragma unroll
        for (int tt = 0; tt < 4; ++tt)
            acc[mt][tt] = (f32x4){0.f, 0.f, 0.f, 0.f};

    #pragma unroll
    for (int s = 0; s < 4; ++s) {
        bf16x8 bfrag[4];
        #pragma unroll
        for (int tt = 0; tt < 4; ++tt)
            bfrag[tt] = *(const bf16x8*)&xs[tt * 16 + col][s * 32 + quad * 8];
        #pragma unroll
        for (int mt = 0; mt < 2; ++mt)
            #pragma unroll
            for (int tt = 0; tt < 4; ++tt)
                acc[mt][tt] = __builtin_amdgcn_mfma_f32_16x16x32_bf16(
                    afrag[mt][s], bfrag[tt], acc[mt][tt], 0, 0, 0);
    }

    // ---- epilogue: all attn/inv reads from LDS; coalesced full-line stores ----
    #pragma unroll
    for (int tt = 0; tt < 4; ++tt) {
        const int n  = tt * 16 + col;
        const int hw = hwbase + n;
        const int p  = hw / 9;
        const int jj = hw - p * 9;
        const int q  = p - p0;                // 0..7
        const int rem = q * 9 + jj;
        #pragma unroll
        for (int mt = 0; mt < 2; ++mt) {
            #pragma unroll
            for (int r = 0; r < 4; ++r) {
                const int c = wbase + mt * 16 + quad * 4 + r;
                const float y  = acc[mt][tt][r] + bias[mt][r];
                const float a  = bf2f(attn_s[c][rem]);
                const float iv = inv_s[c][q];
                const float v  = y * (y + a * iv + 1.0f);
                out[(size_t)c * DHW + (size_t)d * HW + hw] =
                    (v >= 0.f) ? v : 0.2f * v;
            }
        }
    }
}

// ---------------------------------------------------------------------------
// Fallback (known-good) in case ws is too small for inv table.
// ---------------------------------------------------------------------------
__global__ __launch_bounds__(256) void fused_cross_head_fallback(
    const float* __restrict__ x, const float* __restrict__ attn,
    const float* __restrict__ W, const float* __restrict__ bia,
    float* __restrict__ out)
{
    __shared__ __align__(16) short xs[2][48][LDSK];
    __shared__ float inv_lds[COUT][4];

    const int t = threadIdx.x, wv = t >> 6, lane = t & 63;
    const int col = lane & 15, quad = lane >> 4;
    const int blk = blockIdx.x;
    const int pd = blk / 144, hwblk = blk - pd * 144;
    const int hwbase = hwblk * 36;
    const int lbase = pd * NPW + hwblk * 4;

    for (int pair = t; pair < 512; pair += 256) {
        const int c = pair >> 2, p = pair & 3;
        const float* ap = attn + (size_t)c * DHW + (size_t)(lbase + p) * PP;
        int cnt = 0;
        #pragma unroll 27
        for (int q = 0; q < PP; ++q) cnt += (ap[q] != 0.0f) ? 1 : 0;
        inv_lds[c][p] = 1.0f / ((float)cnt + 1e-5f);
    }
    const int wbase = wv * 32;
    bf16x8 afrag[2][4];
    #pragma unroll
    for (int mt = 0; mt < 2; ++mt) {
        const int m = wbase + mt * 16 + col;
        #pragma unroll
        for (int s = 0; s < 4; ++s) {
            const float4* wp4 = (const float4*)(W + m * 128 + s * 32 + quad * 8);
            float4 w0 = wp4[0], w1 = wp4[1];
            bf16x8 f;
            f[0] = f2bf(w0.x); f[1] = f2bf(w0.y); f[2] = f2bf(w0.z); f[3] = f2bf(w0.w);
            f[4] = f2bf(w1.x); f[5] = f2bf(w1.y); f[6] = f2bf(w1.z); f[7] = f2bf(w1.w);
            afrag[mt][s] = f;
        }
    }
    float bias[2][4];
    #pragma unroll
    for (int mt = 0; mt < 2; ++mt)
        #pragma unroll
        for (int r = 0; r < 4; ++r)
            bias[mt][r] = bia[wbase + mt * 16 + quad * 4 + r];

    for (int i = 0; i < 9; ++i) {
        const int buf = i & 1;
        const int d = pd * PATCH + i;
        for (int e = t; e < 1152; e += 256) {
            const int row = e / 9, f4 = e - row * 9;
            const float4 v = *(const float4*)(x + (size_t)row * DHW + (size_t)d * HW
                                              + hwbase + f4 * 4);
            const int n0 = f4 * 4;
            xs[buf][n0 + 0][row] = f2bf(v.x);
            xs[buf][n0 + 1][row] = f2bf(v.y);
            xs[buf][n0 + 2][row] = f2bf(v.z);
            xs[buf][n0 + 3][row] = f2bf(v.w);
        }
        __syncthreads();
        f32x4 acc[2][3];
        #pragma unroll
        for (int mt = 0; mt < 2; ++mt)
            #pragma unroll
            for (int tt = 0; tt < 3; ++tt)
                acc[mt][tt] = (f32x4){0.f, 0.f, 0.f, 0.f};
        #pragma unroll
        for (int s = 0; s < 4; ++s) {
            bf16x8 bfrag[3];
            #pragma unroll
            for (int tt = 0; tt < 3; ++tt)
                bfrag[tt] = *(const bf16x8*)&xs[buf][tt * 16 + col][s * 32 + quad * 8];
            #pragma unroll
            for (int mt = 0; mt < 2; ++mt)
                #pragma unroll
                for (int tt = 0; tt < 3; ++tt)
                    acc[mt][tt] = __builtin_amdgcn_mfma_f32_16x16x32_bf16(
                        afrag[mt][s], bfrag[tt], acc[mt][tt], 0, 0, 0);
        }
        #pragma unroll
        for (int tt = 0; tt < 3; ++tt) {
            const int n = tt * 16 + col;
            if (n < 36) {
                const int p = n / 9, jj = n - p * 9, kk = i * 9 + jj;
                #pragma unroll
                for (int mt = 0; mt < 2; ++mt) {
                    #pragma unroll
                    for (int r = 0; r < 4; ++r) {
                        const int c = wbase + mt * 16 + quad * 4 + r;
                        const float y = acc[mt][tt][r] + bias[mt][r];
                        const float a = attn[(size_t)c * DHW + (size_t)(lbase + p) * PP + kk];
                        const float v = y * (y + a * inv_lds[c][p] + 1.0f);
                        out[(size_t)c * DHW + (size_t)d * HW + hwbase + n] =
                            (v >= 0.f) ? v : 0.2f * v;
                    }
                }
            }
        }
        __syncthreads();
    }
}

extern "C" void kernel_launch(void* const* d_in, const int* in_sizes, int n_in,
                              void* d_out, int out_size, void* d_ws, size_t ws_size,
                              hipStream_t stream) {
    const float* x    = (const float*)d_in[0];
    const float* attn = (const float*)d_in[1];
    const float* W    = (const float*)d_in[2];
    const float* b    = (const float*)d_in[3];
    float* out        = (float*)d_out;

    const size_t inv_bytes = (size_t)COUT * L_TOT * sizeof(float);  // 1.18 MB
    if (ws_size >= inv_bytes) {
        float* inv = (float*)d_ws;
        // 18432 waves x 4 groups = 73728 four-patch groups
        count_ballot<<<dim3(4608), dim3(256), 0, stream>>>(attn, inv);
        fused_main_v3<<<dim3(36 * 81), dim3(256), 0, stream>>>(x, attn, W, b, inv, out);
    } else {
        fused_cross_head_fallback<<<dim3(576), dim3(256), 0, stream>>>(x, attn, W, b, out);
    }
}